// Round 6
// baseline (147.505 us; speedup 1.0000x reference)
//
#include <hip/hip_runtime.h>

#define DEVFN __device__ __forceinline__

constexpr int BNN = 64 * 64 * 64;              // 262144 per output tensor
constexpr float SCALE = 0.08838834764831845f;  // 1/sqrt(128)
constexpr float NSLOPE = 0.01f;

// ---- ws layout (floats) ----
constexpr int OFF_WPRET = 0;       // [64][128]
constexpr int OFF_WQT   = 8192;    // [128][128]
constexpr int OFF_WKT   = 24576;   // [128][128]
constexpr int OFF_WSET  = 40960;   // [128][128]
constexpr int OFF_WSAPT = 57344;   // [96][128]
constexpr int OFF_WAVT  = 69632;   // [128][128]
constexpr int OFF_WF1T  = 86016;   // [128][64]
constexpr int OFF_E     = 98304;    // [4096][128]
constexpr int OFF_Q     = 622592;   // [4096][128]  q1 then q2 (same-row aliasing, safe)
constexpr int OFF_K1    = 1146880;  // [B][128][64] feature-major
constexpr int OFF_K2    = 1671168;  // [B][128][64] feature-major
constexpr int OFF_AVACT = 2195456;  // [B][64][128]
constexpr int OFF_HD    = 2719744;  // [B][64][64]

// ============ register staging (T14 split): issue loads early, LDS-write late ============
// All kernels use 256 threads. Chunks are <=64 rows of width 128 (pitch 132) or
// <=128 rows of width 64 (pitch 68).

DEVFN void ld_f4(int tid, const float* __restrict__ src, float4 (&p)[8], int n4) {
#pragma unroll
  for (int t = 0; t < 8; ++t) {
    const int idx = tid + t * 256;
    if (idx < n4) p[t] = reinterpret_cast<const float4*>(src)[idx];
  }
}

DEVFN void wr128(int tid, float* __restrict__ Bs, const float4 (&p)[8], int n4) {
#pragma unroll
  for (int t = 0; t < 8; ++t) {
    const int idx = tid + t * 256;
    if (idx < n4) {
      const int r = idx >> 5, c = idx & 31;
      *reinterpret_cast<float4*>(&Bs[r * 132 + c * 4]) = p[t];
    }
  }
}

DEVFN void wr64(int tid, float* __restrict__ Bs, const float4 (&p)[8], int n4) {
#pragma unroll
  for (int t = 0; t < 4; ++t) {
    const int idx = tid + t * 256;
    if (idx < n4) {
      const int r = idx >> 4, c = idx & 15;
      *reinterpret_cast<float4*>(&Bs[r * 68 + c * 4]) = p[t];
    }
  }
}

// ============ RPT=2 GEMM cores (256 thr -> 16 rows) ============
// thread: cg=tid&31 (cols c0=4*cg), rg=tid>>5 (rows 2rg, 2rg+1).
// B-read: lanes L and L+32 share an address (broadcast pair); 32 lanes cover the
// full 128-word row = structural minimum bank usage, no extra conflicts.
// A-read: wave sees 2 distinct addresses (broadcast).

DEVFN void gA(int tid, const float* __restrict__ A, int lda,
              const float* __restrict__ Bs, int K,
              float (&a0)[4], float (&a1)[4]) {
  const int c0 = (tid & 31) * 4, r0 = (tid >> 5) * 2;
  const float* __restrict__ A0 = A + r0 * lda;
  const float* __restrict__ A1 = A0 + lda;
#pragma unroll 8
  for (int k = 0; k < K; ++k) {
    const float4 bv = *reinterpret_cast<const float4*>(&Bs[k * 132 + c0]);
    const float x = A0[k], y = A1[k];
    a0[0] += x * bv.x; a0[1] += x * bv.y; a0[2] += x * bv.z; a0[3] += x * bv.w;
    a1[0] += y * bv.x; a1[1] += y * bv.y; a1[2] += y * bv.z; a1[3] += y * bv.w;
  }
}

DEVFN void gA2(int tid, const float* __restrict__ Ax, const float* __restrict__ Ay,
               int lda, const float* __restrict__ Bs, int K,
               float (&p0)[4], float (&p1)[4], float (&q0)[4], float (&q1)[4]) {
  const int c0 = (tid & 31) * 4, r0 = (tid >> 5) * 2;
  const float* __restrict__ X0 = Ax + r0 * lda;
  const float* __restrict__ X1 = X0 + lda;
  const float* __restrict__ Y0 = Ay + r0 * lda;
  const float* __restrict__ Y1 = Y0 + lda;
#pragma unroll 4
  for (int k = 0; k < K; ++k) {
    const float4 bv = *reinterpret_cast<const float4*>(&Bs[k * 132 + c0]);
    const float x0 = X0[k], x1 = X1[k], y0 = Y0[k], y1 = Y1[k];
    p0[0] += x0 * bv.x; p0[1] += x0 * bv.y; p0[2] += x0 * bv.z; p0[3] += x0 * bv.w;
    p1[0] += x1 * bv.x; p1[1] += x1 * bv.y; p1[2] += x1 * bv.z; p1[3] += x1 * bv.w;
    q0[0] += y0 * bv.x; q0[1] += y0 * bv.y; q0[2] += y0 * bv.z; q0[3] += y0 * bv.w;
    q1[0] += y1 * bv.x; q1[1] += y1 * bv.y; q1[2] += y1 * bv.z; q1[3] += y1 * bv.w;
  }
}

// 16x64 output: c0=2*(tid&31), rows 2rg. B pitch 68, float2 reads.
DEVFN void gH(int tid, const float* __restrict__ A, int lda,
              const float* __restrict__ Bs, int K,
              float (&a0)[2], float (&a1)[2]) {
  const int c0 = (tid & 31) * 2, r0 = (tid >> 5) * 2;
  const float* __restrict__ A0 = A + r0 * lda;
  const float* __restrict__ A1 = A0 + lda;
#pragma unroll 8
  for (int k = 0; k < K; ++k) {
    const float2 bv = *reinterpret_cast<const float2*>(&Bs[k * 68 + c0]);
    const float x = A0[k], y = A1[k];
    a0[0] += x * bv.x; a0[1] += x * bv.y;
    a1[0] += y * bv.x; a1[1] += y * bv.y;
  }
}

template<bool ACT, bool HASB>
DEVFN void epi128(int tid, const float (&a0)[4], const float (&a1)[4],
                  float* __restrict__ O, int ldo, const float* __restrict__ bias) {
  const int c0 = (tid & 31) * 4, r0 = (tid >> 5) * 2;
  float t0[4], t1[4];
#pragma unroll
  for (int i = 0; i < 4; ++i) {
    float bv = 0.f;
    if constexpr (HASB) bv = bias[c0 + i];
    float x = a0[i] + bv, y = a1[i] + bv;
    if constexpr (ACT) { x = (x > 0.f) ? x : NSLOPE * x; y = (y > 0.f) ? y : NSLOPE * y; }
    t0[i] = x; t1[i] = y;
  }
  float4 v0; v0.x = t0[0]; v0.y = t0[1]; v0.z = t0[2]; v0.w = t0[3];
  float4 v1; v1.x = t1[0]; v1.y = t1[1]; v1.z = t1[2]; v1.w = t1[3];
  *reinterpret_cast<float4*>(&O[r0 * ldo + c0]) = v0;
  *reinterpret_cast<float4*>(&O[(r0 + 1) * ldo + c0]) = v1;
}

// feature-major global write: O[(c0+i)*64 + rbase + row]
DEVFN void epiK(int tid, const float (&a0)[4], const float (&a1)[4],
                float* __restrict__ O, int rbase) {
  const int c0 = (tid & 31) * 4, r0 = (tid >> 5) * 2;
#pragma unroll
  for (int i = 0; i < 4; ++i) {
    O[(c0 + i) * 64 + rbase + r0]     = a0[i];
    O[(c0 + i) * 64 + rbase + r0 + 1] = a1[i];
  }
}

// ============ score + softmax (256 thr, 16 rows; 4 rows per wave) ============
// Ks chunk: 64 features x 64 agents, pitch 68. q read from global (wave-uniform).
DEVFN void score_half(int tid, const float* __restrict__ qrow, int hoff,
                      const float* __restrict__ Ks, float (&acc)[4]) {
  const int j = tid & 63, iw = tid >> 6;
#pragma unroll 2
  for (int kt = 0; kt < 64; kt += 8) {
    float qv[4][8];
#pragma unroll
    for (int r = 0; r < 4; ++r) {
      *reinterpret_cast<float4*>(&qv[r][0]) =
          *reinterpret_cast<const float4*>(&qrow[(iw * 4 + r) * 128 + hoff + kt]);
      *reinterpret_cast<float4*>(&qv[r][4]) =
          *reinterpret_cast<const float4*>(&qrow[(iw * 4 + r) * 128 + hoff + kt + 4]);
    }
#pragma unroll
    for (int kk = 0; kk < 8; ++kk) {
      const float kv = Ks[(kt + kk) * 68 + j];
#pragma unroll
      for (int r = 0; r < 4; ++r) acc[r] += qv[r][kk] * kv;
    }
  }
}

DEVFN void softmax_write(int tid, float (&acc)[4], float* __restrict__ Wp,
                         float* __restrict__ gout) {
  const int j = tid & 63, iw = tid >> 6;
#pragma unroll
  for (int r = 0; r < 4; ++r) {
    float v = acc[r] * SCALE;
    float m = v;
#pragma unroll
    for (int off = 32; off > 0; off >>= 1) m = fmaxf(m, __shfl_xor(m, off, 64));
    const float p = __expf(v - m);
    float s = p;
#pragma unroll
    for (int off = 32; off > 0; off >>= 1) s += __shfl_xor(s, off, 64);
    const float w = p / s;
    Wp[(iw * 4 + r) * 68 + j] = w;
    gout[(iw * 4 + r) * 64 + j] = w;
  }
}

// ===================== kernels =====================

__global__ void transpose_all(const float* __restrict__ Wpre, const float* __restrict__ Wq,
                              const float* __restrict__ Wk, const float* __restrict__ Wse,
                              const float* __restrict__ Wsap, const float* __restrict__ Wav,
                              const float* __restrict__ Wf1, float* __restrict__ ws) {
  const int m = blockIdx.y;
  const float* src; int Cout, K, off;
  switch (m) {
    case 0: src = Wpre; Cout = 128; K = 64;  off = OFF_WPRET; break;
    case 1: src = Wq;   Cout = 128; K = 128; off = OFF_WQT;   break;
    case 2: src = Wk;   Cout = 128; K = 128; off = OFF_WKT;   break;
    case 3: src = Wse;  Cout = 128; K = 128; off = OFF_WSET;  break;
    case 4: src = Wsap; Cout = 128; K = 96;  off = OFF_WSAPT; break;
    case 5: src = Wav;  Cout = 128; K = 128; off = OFF_WAVT;  break;
    default: src = Wf1; Cout = 64;  K = 128; off = OFF_WF1T;  break;
  }
  const int idx = blockIdx.x * 256 + threadIdx.x;
  if (idx < Cout * K) {
    const int c = idx / K, k = idx - c * K;
    ws[off + k * Cout + c] = src[idx];
  }
}

// P1: grid 256 (b*4+rq), 256 thr, 16 rows. Ping-pong chunks:
// Wsap(64+32) -> Ea/Ep ; Wav(64+64) -> avact/delta ; Wf1(64+64) -> hd ;
// Wpre(64) -> e ; Wq(64+64) -> q1 ; Wk(64+64) -> k1.
__global__ __launch_bounds__(256) void P1(const float* __restrict__ states,
                                          const float* __restrict__ policies,
                                          const float* __restrict__ actions,
                                          const float* __restrict__ b_sap,
                                          const float* __restrict__ b_se_pre,
                                          float* __restrict__ ws) {
  __shared__ float B0[8704], B1[8704];
  __shared__ float Xa[16 * 100], Xp[16 * 100];
  __shared__ float Ea[16 * 132], Ep[16 * 132], Dd[16 * 132], Er[16 * 132];
  const int tid = threadIdx.x;
  const int b = blockIdx.x >> 2, rq = blockIdx.x & 3;
  const int r0g = b * 64 + rq * 16;
  float4 pre[8];

  // prologue: chunk0 loads in flight while X stages
  ld_f4(tid, ws + OFF_WSAPT, pre, 2048);
  for (int idx = tid; idx < 1024; idx += 256) {
    const int r = idx >> 6, c = idx & 63;
    const float s = states[(r0g + r) * 64 + c];
    Xa[r * 100 + c] = s;
    Xp[r * 100 + c] = s;
  }
  {
    const int r = tid >> 5, c = tid & 31;
    const int rr = r >> 1;  // 8 rows per pass, 2 passes
    Xa[(rr * 2 + (r & 1)) * 100 + 64 + c] = actions[(r0g + rr * 2 + (r & 1)) * 32 + c];
    Xp[(rr * 2 + (r & 1)) * 100 + 64 + c] = policies[(r0g + rr * 2 + (r & 1)) * 32 + c];
  }
  {
    const int idx = tid + 256;
    const int r = idx >> 5, c = idx & 31;
    Xa[r * 100 + 64 + c] = actions[(r0g + r) * 32 + c];
    Xp[r * 100 + 64 + c] = policies[(r0g + r) * 32 + c];
  }
  wr128(tid, B0, pre, 2048);
  __syncthreads();

  float aa0[4] = {}, aa1[4] = {}, ap0[4] = {}, ap1[4] = {};
  // step0: Esap part1 (K=64)
  ld_f4(tid, ws + OFF_WSAPT + 8192, pre, 1024);
  gA2(tid, Xa, Xp, 100, B0, 64, aa0, aa1, ap0, ap1);
  __syncthreads();
  wr128(tid, B1, pre, 1024);
  __syncthreads();
  // step1: Esap tail (K=32) -> Ea, Ep ; Ep -= Ea
  ld_f4(tid, ws + OFF_WAVT, pre, 2048);
  gA2(tid, Xa + 64, Xp + 64, 100, B1, 32, aa0, aa1, ap0, ap1);
  epi128<true, true>(tid, aa0, aa1, Ea, 132, b_sap);
  epi128<true, true>(tid, ap0, ap1, Ep, 132, b_sap);
  __syncthreads();
  for (int idx = tid; idx < 2048; idx += 256) {
    const int r = idx >> 7, c = idx & 127;
    Ep[r * 132 + c] -= Ea[r * 132 + c];
  }
  __syncthreads();
  wr128(tid, B0, pre, 2048);
  __syncthreads();

  float av0[4] = {}, av1[4] = {}, dl0[4] = {}, dl1[4] = {};
  // step2: av/delta part1
  ld_f4(tid, ws + OFF_WAVT + 8192, pre, 2048);
  gA2(tid, Ea, Ep, 132, B0, 64, av0, av1, dl0, dl1);
  __syncthreads();
  wr128(tid, B1, pre, 2048);
  __syncthreads();
  // step3: av/delta part2 -> avact (global), Dd (LDS)
  ld_f4(tid, ws + OFF_WF1T, pre, 1024);
  gA2(tid, Ea + 64, Ep + 64, 132, B1, 64, av0, av1, dl0, dl1);
  epi128<false, false>(tid, av0, av1, ws + OFF_AVACT + r0g * 128, 128, nullptr);
  epi128<false, false>(tid, dl0, dl1, Dd, 132, nullptr);
  __syncthreads();
  wr64(tid, B0, pre, 1024);
  __syncthreads();

  float ah0[2] = {}, ah1[2] = {};
  // step4: hd part1
  ld_f4(tid, ws + OFF_WF1T + 4096, pre, 1024);
  gH(tid, Dd, 132, B0, 64, ah0, ah1);
  __syncthreads();
  wr64(tid, B1, pre, 1024);
  __syncthreads();
  // step5: hd part2 -> ws.HD (global float2)
  ld_f4(tid, ws + OFF_WPRET, pre, 2048);
  gH(tid, Dd + 64, 132, B1, 64, ah0, ah1);
  {
    const int c0 = (tid & 31) * 2, r0 = (tid >> 5) * 2;
    float* hd = ws + OFF_HD + (r0g + r0) * 64 + c0;
    float2 v0; v0.x = ah0[0]; v0.y = ah0[1];
    float2 v1; v1.x = ah1[0]; v1.y = ah1[1];
    *reinterpret_cast<float2*>(hd) = v0;
    *reinterpret_cast<float2*>(hd + 64) = v1;
  }
  __syncthreads();
  wr128(tid, B0, pre, 2048);
  __syncthreads();

  float ae0[4] = {}, ae1[4] = {};
  // step6: e = lrelu(states @ Wpre^T + b) -> Er LDS + ws.E global
  ld_f4(tid, ws + OFF_WQT, pre, 2048);
  gA(tid, Xa, 100, B0, 64, ae0, ae1);
  {
    const int c0 = (tid & 31) * 4, r0 = (tid >> 5) * 2;
    float t0[4], t1[4];
#pragma unroll
    for (int i = 0; i < 4; ++i) {
      const float bv = b_se_pre[c0 + i];
      float x = ae0[i] + bv, y = ae1[i] + bv;
      t0[i] = (x > 0.f) ? x : NSLOPE * x;
      t1[i] = (y > 0.f) ? y : NSLOPE * y;
    }
    float4 v0; v0.x = t0[0]; v0.y = t0[1]; v0.z = t0[2]; v0.w = t0[3];
    float4 v1; v1.x = t1[0]; v1.y = t1[1]; v1.z = t1[2]; v1.w = t1[3];
    *reinterpret_cast<float4*>(&Er[r0 * 132 + c0]) = v0;
    *reinterpret_cast<float4*>(&Er[(r0 + 1) * 132 + c0]) = v1;
    *reinterpret_cast<float4*>(&ws[OFF_E + (r0g + r0) * 128 + c0]) = v0;
    *reinterpret_cast<float4*>(&ws[OFF_E + (r0g + r0 + 1) * 128 + c0]) = v1;
  }
  __syncthreads();
  wr128(tid, B1, pre, 2048);
  __syncthreads();

  float q0[4] = {}, q1[4] = {};
  // step7: q1 part1
  ld_f4(tid, ws + OFF_WQT + 8192, pre, 2048);
  gA(tid, Er, 132, B1, 64, q0, q1);
  __syncthreads();
  wr128(tid, B0, pre, 2048);
  __syncthreads();
  // step8: q1 part2 -> ws.Q
  ld_f4(tid, ws + OFF_WKT, pre, 2048);
  gA(tid, Er + 64, 132, B0, 64, q0, q1);
  epi128<false, false>(tid, q0, q1, ws + OFF_Q + r0g * 128, 128, nullptr);
  __syncthreads();
  wr128(tid, B1, pre, 2048);
  __syncthreads();

  float k0[4] = {}, k1[4] = {};
  // step9: k1 part1
  ld_f4(tid, ws + OFF_WKT + 8192, pre, 2048);
  gA(tid, Er, 132, B1, 64, k0, k1);
  __syncthreads();
  wr128(tid, B0, pre, 2048);
  __syncthreads();
  // step10: k1 part2 -> ws.K1 feature-major
  gA(tid, Er + 64, 132, B0, 64, k0, k1);
  epiK(tid, k0, k1, ws + OFF_K1 + b * 8192, rq * 16);
}

// P3: grid 256, 256 thr, 16 rows. score1+softmax -> w_pre ; av_pre ; se ; q2/k2.
__global__ __launch_bounds__(256) void P3(const float* __restrict__ b_se,
                                          float* __restrict__ ws,
                                          float* __restrict__ out) {
  __shared__ float B0[8704], B1[8704];
  __shared__ float Wp[16 * 68], AV[16 * 132], SEr[16 * 132];
  const int tid = threadIdx.x;
  const int b = blockIdx.x >> 2, rq = blockIdx.x & 3;
  const int r0g = b * 64 + rq * 16;
  const float* __restrict__ qrow = ws + OFF_Q + r0g * 128;
  float4 pre[8];

  ld_f4(tid, ws + OFF_K1 + b * 8192, pre, 1024);
  wr64(tid, B0, pre, 1024);
  __syncthreads();

  float sc[4] = {};
  // step0: score h=0
  ld_f4(tid, ws + OFF_K1 + b * 8192 + 4096, pre, 1024);
  score_half(tid, qrow, 0, B0, sc);
  __syncthreads();
  wr64(tid, B1, pre, 1024);
  __syncthreads();
  // step1: score h=1 + softmax -> Wp + w_pre
  ld_f4(tid, ws + OFF_E + b * 8192, pre, 2048);
  score_half(tid, qrow, 64, B1, sc);
  softmax_write(tid, sc, Wp, out + BNN + b * 4096 + rq * 1024);
  __syncthreads();
  wr128(tid, B0, pre, 2048);
  __syncthreads();
  // step2: av_pre = w_pre @ e[b] (K=64)
  ld_f4(tid, ws + OFF_WSET, pre, 2048);
  {
    float v0[4] = {}, v1[4] = {};
    gA(tid, Wp, 68, B0, 64, v0, v1);
    epi128<false, false>(tid, v0, v1, AV, 132, nullptr);
  }
  __syncthreads();
  wr128(tid, B1, pre, 2048);
  __syncthreads();

  float s0[4] = {}, s1[4] = {};
  // step3: se part1
  ld_f4(tid, ws + OFF_WSET + 8192, pre, 2048);
  gA(tid, AV, 132, B1, 64, s0, s1);
  __syncthreads();
  wr128(tid, B0, pre, 2048);
  __syncthreads();
  // step4: se part2 -> SEr
  ld_f4(tid, ws + OFF_WQT, pre, 2048);
  gA(tid, AV + 64, 132, B0, 64, s0, s1);
  epi128<true, true>(tid, s0, s1, SEr, 132, b_se);
  __syncthreads();
  wr128(tid, B1, pre, 2048);
  __syncthreads();

  float q0[4] = {}, q1[4] = {};
  // step5: q2 part1
  ld_f4(tid, ws + OFF_WQT + 8192, pre, 2048);
  gA(tid, SEr, 132, B1, 64, q0, q1);
  __syncthreads();
  wr128(tid, B0, pre, 2048);
  __syncthreads();
  // step6: q2 part2 -> ws.Q (own rows only; score already done)
  ld_f4(tid, ws + OFF_WKT, pre, 2048);
  gA(tid, SEr + 64, 132, B0, 64, q0, q1);
  epi128<false, false>(tid, q0, q1, ws + OFF_Q + r0g * 128, 128, nullptr);
  __syncthreads();
  wr128(tid, B1, pre, 2048);
  __syncthreads();

  float k0[4] = {}, k1[4] = {};
  // step7: k2 part1
  ld_f4(tid, ws + OFF_WKT + 8192, pre, 2048);
  gA(tid, SEr, 132, B1, 64, k0, k1);
  __syncthreads();
  wr128(tid, B0, pre, 2048);
  __syncthreads();
  // step8: k2 part2 -> ws.K2
  gA(tid, SEr + 64, 132, B0, 64, k0, k1);
  epiK(tid, k0, k1, ws + OFF_K2 + b * 8192, rq * 16);
}

// P4: grid 256, 256 thr, 16 rows. score2 -> w ; node ; h_base ; head -> value.
__global__ __launch_bounds__(256) void P4(const float* __restrict__ Wf2g,
                                          float* __restrict__ ws,
                                          float* __restrict__ out) {
  __shared__ float B0[8704], B1[8704];
  __shared__ float Wp[16 * 68], NB[16 * 132], Hb[16 * 66];
  __shared__ float Hd[64 * 69];
  __shared__ float Wf2s[64];
  const int tid = threadIdx.x;
  const int b = blockIdx.x >> 2, rq = blockIdx.x & 3;
  const int r0g = b * 64 + rq * 16;
  const float* __restrict__ qrow = ws + OFF_Q + r0g * 128;
  float4 pre[8];

  ld_f4(tid, ws + OFF_K2 + b * 8192, pre, 1024);
  for (int idx = tid; idx < 4096; idx += 256)
    Hd[(idx >> 6) * 69 + (idx & 63)] = ws[OFF_HD + b * 4096 + idx];
  if (tid < 64) Wf2s[tid] = Wf2g[tid];
  wr64(tid, B0, pre, 1024);
  __syncthreads();

  float sc[4] = {};
  // step0: score h=0
  ld_f4(tid, ws + OFF_K2 + b * 8192 + 4096, pre, 1024);
  score_half(tid, qrow, 0, B0, sc);
  __syncthreads();
  wr64(tid, B1, pre, 1024);
  __syncthreads();
  // step1: score h=1 + softmax -> Wp + w
  ld_f4(tid, ws + OFF_AVACT + b * 8192, pre, 2048);
  score_half(tid, qrow, 64, B1, sc);
  softmax_write(tid, sc, Wp, out + 2 * BNN + b * 4096 + rq * 1024);
  __syncthreads();
  wr128(tid, B0, pre, 2048);
  __syncthreads();
  // step2: node = w @ av_act (K=64)
  ld_f4(tid, ws + OFF_WF1T, pre, 1024);
  {
    float n0[4] = {}, n1[4] = {};
    gA(tid, Wp, 68, B0, 64, n0, n1);
    epi128<false, false>(tid, n0, n1, NB, 132, nullptr);
  }
  __syncthreads();
  wr64(tid, B1, pre, 1024);
  __syncthreads();

  float h0[2] = {}, h1[2] = {};
  // step3: h_base part1
  ld_f4(tid, ws + OFF_WF1T + 4096, pre, 1024);
  gH(tid, NB, 132, B1, 64, h0, h1);
  __syncthreads();
  wr64(tid, B0, pre, 1024);
  __syncthreads();
  // step4: h_base part2 -> Hb (pitch 66)
  gH(tid, NB + 64, 132, B0, 64, h0, h1);
  {
    const int c0 = (tid & 31) * 2, r0 = (tid >> 5) * 2;
    float2 v0; v0.x = h0[0]; v0.y = h0[1];
    float2 v1; v1.x = h1[0]; v1.y = h1[1];
    *reinterpret_cast<float2*>(&Hb[r0 * 66 + c0]) = v0;
    *reinterpret_cast<float2*>(&Hb[(r0 + 1) * 66 + c0]) = v1;
  }
  __syncthreads();

  // head: value[i][j] = sum_f lrelu(Hb[i,f] + w[i,j]*Hd[j,f]) * Wf2[f]
  const int j = tid & 63, iw = tid >> 6;
  float wv[4], a4[4] = {0.f, 0.f, 0.f, 0.f};
#pragma unroll
  for (int r = 0; r < 4; ++r) wv[r] = Wp[(iw * 4 + r) * 68 + j];
  for (int f = 0; f < 64; ++f) {
    const float hdv = Hd[j * 69 + f];
    const float wf = Wf2s[f];
#pragma unroll
    for (int r = 0; r < 4; ++r) {
      float t = Hb[(iw * 4 + r) * 66 + f] + wv[r] * hdv;
      t = (t > 0.f) ? t : NSLOPE * t;
      a4[r] += t * wf;
    }
  }
#pragma unroll
  for (int r = 0; r < 4; ++r)
    out[(r0g + iw * 4 + r) * 64 + j] = a4[r];
}

extern "C" void kernel_launch(void* const* d_in, const int* in_sizes, int n_in,
                              void* d_out, int out_size, void* d_ws, size_t ws_size,
                              hipStream_t stream) {
  const float* states   = (const float*)d_in[0];
  const float* policies = (const float*)d_in[1];
  const float* actions  = (const float*)d_in[2];
  const float* W_se_pre = (const float*)d_in[3];
  const float* b_se_pre = (const float*)d_in[4];
  const float* W_key    = (const float*)d_in[5];
  const float* W_query  = (const float*)d_in[6];
  const float* W_se     = (const float*)d_in[7];
  const float* b_se     = (const float*)d_in[8];
  const float* W_sap    = (const float*)d_in[9];
  const float* b_sap    = (const float*)d_in[10];
  const float* W_av     = (const float*)d_in[11];
  const float* W_f1     = (const float*)d_in[12];
  const float* W_f2     = (const float*)d_in[13];
  float* out = (float*)d_out;
  float* ws  = (float*)d_ws;

  transpose_all<<<dim3(64, 7), dim3(256), 0, stream>>>(
      W_se_pre, W_query, W_key, W_se, W_sap, W_av, W_f1, ws);
  P1<<<dim3(256), dim3(256), 0, stream>>>(states, policies, actions, b_sap, b_se_pre, ws);
  P3<<<dim3(256), dim3(256), 0, stream>>>(b_se, ws, out);
  P4<<<dim3(256), dim3(256), 0, stream>>>(W_f2, ws, out);
}

// Round 7
// 79.284 us; speedup vs baseline: 1.8605x; 1.8605x over previous
//
#include <hip/hip_runtime.h>

#define DEVFN __device__ __forceinline__

constexpr int BNN = 64 * 64 * 64;              // 262144 per output tensor
constexpr float SCALE = 0.08838834764831845f;  // 1/sqrt(128)
constexpr float NSLOPE = 0.01f;

// ---- ws layout (floats) ---- (total 11.93 MB, proven available in R4/R5)
constexpr int OFF_WPRET = 0;       // [64][128]
constexpr int OFF_WQT   = 8192;    // [128][128] (used by make_M only)
constexpr int OFF_M     = 24576;   // [128][128]  M = Wq^T Wk (overwrites WKT slot)
constexpr int OFF_WSET  = 40960;   // [128][128]
constexpr int OFF_WSAPT = 57344;   // [96][128]
constexpr int OFF_WAVT  = 69632;   // [128][128]
constexpr int OFF_WF1T  = 86016;   // [128][64]
constexpr int OFF_E     = 98304;    // [4096][128] e row-major
constexpr int OFF_Q     = 622592;   // [4096][128] f then f2 (same-row aliasing, safe)
constexpr int OFF_ET    = 1146880;  // [B][128][64] e feature-major
constexpr int OFF_SET   = 1671168;  // [B][128][64] se feature-major
constexpr int OFF_AVACT = 2195456;  // [B][64][128]
constexpr int OFF_HD    = 2719744;  // [B][64][64]

// ============ staging: global (tight) -> LDS (padded pitch), 512 threads ============

// [rows<=64][128] -> pitch 132
DEVFN void st128(int tid, const float* __restrict__ src, float* __restrict__ Bs, int rows) {
  const int n4 = rows * 32;
  for (int idx = tid; idx < n4; idx += 512) {
    const int r = idx >> 5, c = idx & 31;
    *reinterpret_cast<float4*>(&Bs[r * 132 + c * 4]) =
        *reinterpret_cast<const float4*>(&src[r * 128 + c * 4]);
  }
}

// [64][64] -> pitch 68
DEVFN void st64x(int tid, const float* __restrict__ src, float* __restrict__ Bs) {
  for (int idx = tid; idx < 1024; idx += 512) {
    const int r = idx >> 4, c = idx & 15;
    *reinterpret_cast<float4*>(&Bs[r * 68 + c * 4]) =
        *reinterpret_cast<const float4*>(&src[r * 64 + c * 4]);
  }
}

// ============ LDS-fed GEMM cores: 512 thr, 16 rows x 128 cols, 1 row x 4 cols/thread ===
// cg=tid&31 (c0=4cg), rg=tid>>5. B: 32 distinct float4/wave (2-way) = conflict-free.

DEVFN void g1(int tid, const float* __restrict__ A, int lda,
              const float* __restrict__ Bs, int K, float (&acc)[4]) {
  const int c0 = (tid & 31) * 4, rg = tid >> 5;
#pragma unroll 8
  for (int k = 0; k < K; ++k) {
    const float4 bv = *reinterpret_cast<const float4*>(&Bs[k * 132 + c0]);
    const float a = A[rg * lda + k];
    acc[0] += a * bv.x; acc[1] += a * bv.y; acc[2] += a * bv.z; acc[3] += a * bv.w;
  }
}

DEVFN void g2A(int tid, const float* __restrict__ A0, const float* __restrict__ A1,
               int lda, const float* __restrict__ Bs, int K,
               float (&a0)[4], float (&a1)[4]) {
  const int c0 = (tid & 31) * 4, rg = tid >> 5;
#pragma unroll 4
  for (int k = 0; k < K; ++k) {
    const float4 bv = *reinterpret_cast<const float4*>(&Bs[k * 132 + c0]);
    const float x = A0[rg * lda + k];
    const float y = A1[rg * lda + k];
    a0[0] += x * bv.x; a0[1] += x * bv.y; a0[2] += x * bv.z; a0[3] += x * bv.w;
    a1[0] += y * bv.x; a1[1] += y * bv.y; a1[2] += y * bv.z; a1[3] += y * bv.w;
  }
}

// 16 rows x 64 cols: c0=2*(tid&31), rg=tid>>5. B pitch 68 float2 (2-way = free).
DEVFN void gH(int tid, const float* __restrict__ A, int lda,
              const float* __restrict__ Bs, int K, float (&acc)[2]) {
  const int c0 = (tid & 31) * 2, rg = tid >> 5;
#pragma unroll 8
  for (int k = 0; k < K; ++k) {
    const float2 bv = *reinterpret_cast<const float2*>(&Bs[k * 68 + c0]);
    const float a = A[rg * lda + k];
    acc[0] += a * bv.x; acc[1] += a * bv.y;
  }
}

template<bool ACT, bool HASB>
DEVFN void epi(int tid, const float (&acc)[4], float* __restrict__ O, int ldo,
               const float* __restrict__ bias) {
  const int c0 = (tid & 31) * 4, rg = tid >> 5;
  float t[4];
#pragma unroll
  for (int i = 0; i < 4; ++i) {
    float x = acc[i];
    if constexpr (HASB) x += bias[c0 + i];
    if constexpr (ACT) x = (x > 0.f) ? x : NSLOPE * x;
    t[i] = x;
  }
  float4 v; v.x = t[0]; v.y = t[1]; v.z = t[2]; v.w = t[3];
  *reinterpret_cast<float4*>(&O[rg * ldo + c0]) = v;
}

// ============ score + softmax: 512 thr, 16 rows (2 rows per wave) ============
// Qs: [16][132] LDS (broadcast). Ks: [64 feat][64 agents] pitch 68.
DEVFN void score_half(int tid, const float* __restrict__ Qs, int hoff,
                      const float* __restrict__ Ks, float (&acc)[2]) {
  const int j = tid & 63, iw = tid >> 6;
#pragma unroll 2
  for (int kt = 0; kt < 64; kt += 8) {
    float qv[2][8];
#pragma unroll
    for (int r = 0; r < 2; ++r) {
      *reinterpret_cast<float4*>(&qv[r][0]) =
          *reinterpret_cast<const float4*>(&Qs[(iw * 2 + r) * 132 + hoff + kt]);
      *reinterpret_cast<float4*>(&qv[r][4]) =
          *reinterpret_cast<const float4*>(&Qs[(iw * 2 + r) * 132 + hoff + kt + 4]);
    }
#pragma unroll
    for (int kk = 0; kk < 8; ++kk) {
      const float kv = Ks[(kt + kk) * 68 + j];
      acc[0] += qv[0][kk] * kv;
      acc[1] += qv[1][kk] * kv;
    }
  }
}

DEVFN void softmax_write(int tid, float (&acc)[2], float* __restrict__ Wp,
                         float* __restrict__ gout) {
  const int j = tid & 63, iw = tid >> 6;
#pragma unroll
  for (int r = 0; r < 2; ++r) {
    float v = acc[r] * SCALE;
    float m = v;
#pragma unroll
    for (int off = 32; off > 0; off >>= 1) m = fmaxf(m, __shfl_xor(m, off, 64));
    const float p = __expf(v - m);
    float s = p;
#pragma unroll
    for (int off = 32; off > 0; off >>= 1) s += __shfl_xor(s, off, 64);
    const float w = p / s;
    Wp[(iw * 2 + r) * 68 + j] = w;
    gout[(iw * 2 + r) * 64 + j] = w;
  }
}

// ===================== kernels =====================

__global__ void transpose_all(const float* __restrict__ Wpre, const float* __restrict__ Wq,
                              const float* __restrict__ Wse, const float* __restrict__ Wsap,
                              const float* __restrict__ Wav, const float* __restrict__ Wf1,
                              float* __restrict__ ws) {
  const int m = blockIdx.y;
  const float* src; int Cout, K, off;
  switch (m) {
    case 0: src = Wpre; Cout = 128; K = 64;  off = OFF_WPRET; break;
    case 1: src = Wq;   Cout = 128; K = 128; off = OFF_WQT;   break;
    case 2: src = Wse;  Cout = 128; K = 128; off = OFF_WSET;  break;
    case 3: src = Wsap; Cout = 128; K = 96;  off = OFF_WSAPT; break;
    case 4: src = Wav;  Cout = 128; K = 128; off = OFF_WAVT;  break;
    default: src = Wf1; Cout = 64;  K = 128; off = OFF_WF1T;  break;
  }
  const int idx = blockIdx.x * 256 + threadIdx.x;
  if (idx < Cout * K) {
    const int c = idx / K, k = idx - c * K;
    ws[off + k * Cout + c] = src[idx];
  }
}

// M = Wq^T @ Wk: M[d][d'] = sum_r WQT[d][r] * Wkey[r][d'].  Grid 8 x 512, 16 rows.
__global__ __launch_bounds__(512) void make_M(const float* __restrict__ Wkey,
                                              float* __restrict__ ws) {
  __shared__ float As[16 * 132];
  __shared__ float Bs[64 * 132];
  const int tid = threadIdx.x;
  const int r0 = blockIdx.x * 16;
  {
    const int r = tid >> 5, c = tid & 31;
    *reinterpret_cast<float4*>(&As[r * 132 + c * 4]) =
        *reinterpret_cast<const float4*>(&ws[OFF_WQT + (r0 + r) * 128 + c * 4]);
  }
  float acc[4] = {};
  st128(tid, Wkey, Bs, 64);
  __syncthreads();
  g1(tid, As, 132, Bs, 64, acc);
  __syncthreads();
  st128(tid, Wkey + 8192, Bs, 64);
  __syncthreads();
  g1(tid, As + 64, 132, Bs, 64, acc);
  epi<false, false>(tid, acc, ws + OFF_M + r0 * 128, 128, nullptr);
}

// P1: grid 256 (b*4+rq), 512 thr, 16 rows: Esap(dual) -> av/delta(dual) -> hd ;
// e (row-major + feature-major) -> f = e@M.
__global__ __launch_bounds__(512) void P1(const float* __restrict__ states,
                                          const float* __restrict__ policies,
                                          const float* __restrict__ actions,
                                          const float* __restrict__ b_sap,
                                          const float* __restrict__ b_se_pre,
                                          float* __restrict__ ws) {
  __shared__ float Xa[16 * 100], Xp[16 * 100];
  __shared__ float Ea[16 * 132], Ep[16 * 132], Dd[16 * 132], Er[16 * 132];
  __shared__ float Bs[64 * 132];
  const int tid = threadIdx.x;
  const int b = blockIdx.x >> 2, rq = blockIdx.x & 3;
  const int r0g = b * 64 + rq * 16;

  for (int idx = tid; idx < 1024; idx += 512) {
    const int r = idx >> 6, c = idx & 63;
    const float s = states[(r0g + r) * 64 + c];
    Xa[r * 100 + c] = s;
    Xp[r * 100 + c] = s;
  }
  {
    const int r = tid >> 5, c = tid & 31;
    Xa[r * 100 + 64 + c] = actions[(r0g + r) * 32 + c];
    Xp[r * 100 + 64 + c] = policies[(r0g + r) * 32 + c];
  }
  st128(tid, ws + OFF_WSAPT, Bs, 64);
  __syncthreads();
  float aa[4] = {}, ap[4] = {};
  g2A(tid, Xa, Xp, 100, Bs, 64, aa, ap);
  __syncthreads();
  st128(tid, ws + OFF_WSAPT + 8192, Bs, 32);
  __syncthreads();
  g2A(tid, Xa + 64, Xp + 64, 100, Bs, 32, aa, ap);
  epi<true, true>(tid, aa, Ea, 132, b_sap);
  epi<true, true>(tid, ap, Ep, 132, b_sap);
  __syncthreads();
  for (int idx = tid; idx < 2048; idx += 512) {
    const int r = idx >> 7, c = idx & 127;
    Ep[r * 132 + c] -= Ea[r * 132 + c];
  }
  __syncthreads();
  // av_act / delta (K=128 in 2 chunks)
  st128(tid, ws + OFF_WAVT, Bs, 64);
  __syncthreads();
  float av[4] = {}, dl[4] = {};
  g2A(tid, Ea, Ep, 132, Bs, 64, av, dl);
  __syncthreads();
  st128(tid, ws + OFF_WAVT + 8192, Bs, 64);
  __syncthreads();
  g2A(tid, Ea + 64, Ep + 64, 132, Bs, 64, av, dl);
  epi<false, false>(tid, av, ws + OFF_AVACT + r0g * 128, 128, nullptr);
  epi<false, false>(tid, dl, Dd, 132, nullptr);
  __syncthreads();
  // hd = delta @ Wf1^T (K=128, 2 chunks, 64 cols)
  st64x(tid, ws + OFF_WF1T, Bs);
  __syncthreads();
  float ah[2] = {};
  gH(tid, Dd, 132, Bs, 64, ah);
  __syncthreads();
  st64x(tid, ws + OFF_WF1T + 4096, Bs);
  __syncthreads();
  gH(tid, Dd + 64, 132, Bs, 64, ah);
  {
    const int c0 = (tid & 31) * 2, rg = tid >> 5;
    float2 v; v.x = ah[0]; v.y = ah[1];
    *reinterpret_cast<float2*>(&ws[OFF_HD + (r0g + rg) * 64 + c0]) = v;
  }
  __syncthreads();
  // e = lrelu(states @ Wpre^T + b) -> Er + ws.E (row-major) + ws.ET (feature-major)
  st128(tid, ws + OFF_WPRET, Bs, 64);
  __syncthreads();
  {
    float ae[4] = {};
    g1(tid, Xa, 100, Bs, 64, ae);
    const int c0 = (tid & 31) * 4, rg = tid >> 5;
    float t[4];
#pragma unroll
    for (int i = 0; i < 4; ++i) {
      float x = ae[i] + b_se_pre[c0 + i];
      t[i] = (x > 0.f) ? x : NSLOPE * x;
    }
    float4 v; v.x = t[0]; v.y = t[1]; v.z = t[2]; v.w = t[3];
    *reinterpret_cast<float4*>(&Er[rg * 132 + c0]) = v;
    *reinterpret_cast<float4*>(&ws[OFF_E + (r0g + rg) * 128 + c0]) = v;
    float* et = ws + OFF_ET + b * 8192;
#pragma unroll
    for (int i = 0; i < 4; ++i) et[(c0 + i) * 64 + rq * 16 + rg] = t[i];
  }
  __syncthreads();
  // f = e @ M (K=128, 2 chunks)
  st128(tid, ws + OFF_M, Bs, 64);
  __syncthreads();
  float af[4] = {};
  g1(tid, Er, 132, Bs, 64, af);
  __syncthreads();
  st128(tid, ws + OFF_M + 8192, Bs, 64);
  __syncthreads();
  g1(tid, Er + 64, 132, Bs, 64, af);
  epi<false, false>(tid, af, ws + OFF_Q + r0g * 128, 128, nullptr);
}

// P3: grid 256, 512 thr, 16 rows. score1(f @ eT)+softmax -> w_pre ; av_pre ; se
// (row + feature-major) ; f2 = se@M.
__global__ __launch_bounds__(512) void P3(const float* __restrict__ b_se,
                                          float* __restrict__ ws,
                                          float* __restrict__ out) {
  __shared__ float Qs[16 * 132];
  __shared__ float Bs[64 * 132];
  __shared__ float Wp[16 * 68], AV[16 * 132], SEr[16 * 132];
  const int tid = threadIdx.x;
  const int b = blockIdx.x >> 2, rq = blockIdx.x & 3;
  const int r0g = b * 64 + rq * 16;

  {
    const int r = tid >> 5, c = tid & 31;
    *reinterpret_cast<float4*>(&Qs[r * 132 + c * 4]) =
        *reinterpret_cast<const float4*>(&ws[OFF_Q + (r0g + r) * 128 + c * 4]);
  }
  st64x(tid, ws + OFF_ET + b * 8192, Bs);
  __syncthreads();
  float sc[2] = {};
  score_half(tid, Qs, 0, Bs, sc);
  __syncthreads();
  st64x(tid, ws + OFF_ET + b * 8192 + 4096, Bs);
  __syncthreads();
  score_half(tid, Qs, 64, Bs, sc);
  softmax_write(tid, sc, Wp, out + BNN + b * 4096 + rq * 1024);
  __syncthreads();
  // av_pre = w_pre @ e[b] (K=64)
  st128(tid, ws + OFF_E + b * 8192, Bs, 64);
  __syncthreads();
  {
    float a[4] = {};
    g1(tid, Wp, 68, Bs, 64, a);
    epi<false, false>(tid, a, AV, 132, nullptr);
  }
  __syncthreads();
  // se = lrelu(av_pre @ Wse^T + b_se) (K=128, 2 chunks) -> SEr + ws.SET
  st128(tid, ws + OFF_WSET, Bs, 64);
  __syncthreads();
  float as[4] = {};
  g1(tid, AV, 132, Bs, 64, as);
  __syncthreads();
  st128(tid, ws + OFF_WSET + 8192, Bs, 64);
  __syncthreads();
  g1(tid, AV + 64, 132, Bs, 64, as);
  {
    const int c0 = (tid & 31) * 4, rg = tid >> 5;
    float t[4];
#pragma unroll
    for (int i = 0; i < 4; ++i) {
      float x = as[i] + b_se[c0 + i];
      t[i] = (x > 0.f) ? x : NSLOPE * x;
    }
    float4 v; v.x = t[0]; v.y = t[1]; v.z = t[2]; v.w = t[3];
    *reinterpret_cast<float4*>(&SEr[rg * 132 + c0]) = v;
    float* set = ws + OFF_SET + b * 8192;
#pragma unroll
    for (int i = 0; i < 4; ++i) set[(c0 + i) * 64 + rq * 16 + rg] = t[i];
  }
  __syncthreads();
  // f2 = se @ M (K=128, 2 chunks) -> ws.Q (own rows)
  st128(tid, ws + OFF_M, Bs, 64);
  __syncthreads();
  float af[4] = {};
  g1(tid, SEr, 132, Bs, 64, af);
  __syncthreads();
  st128(tid, ws + OFF_M + 8192, Bs, 64);
  __syncthreads();
  g1(tid, SEr + 64, 132, Bs, 64, af);
  epi<false, false>(tid, af, ws + OFF_Q + r0g * 128, 128, nullptr);
}

// P4: grid 256, 512 thr, 16 rows. score2(f2 @ seT) -> w ; node ; h_base ; head.
__global__ __launch_bounds__(512) void P4(const float* __restrict__ Wf2g,
                                          float* __restrict__ ws,
                                          float* __restrict__ out) {
  __shared__ float Qs[16 * 132];
  __shared__ float Bs[64 * 132];
  __shared__ float Wp[16 * 68], NB[16 * 132], Hb[16 * 66];
  __shared__ float Hd[64 * 69];
  __shared__ float Wf2s[64];
  const int tid = threadIdx.x;
  const int b = blockIdx.x >> 2, rq = blockIdx.x & 3;
  const int r0g = b * 64 + rq * 16;

  for (int idx = tid; idx < 4096; idx += 512)
    Hd[(idx >> 6) * 69 + (idx & 63)] = ws[OFF_HD + b * 4096 + idx];
  if (tid < 64) Wf2s[tid] = Wf2g[tid];
  {
    const int r = tid >> 5, c = tid & 31;
    *reinterpret_cast<float4*>(&Qs[r * 132 + c * 4]) =
        *reinterpret_cast<const float4*>(&ws[OFF_Q + (r0g + r) * 128 + c * 4]);
  }
  st64x(tid, ws + OFF_SET + b * 8192, Bs);
  __syncthreads();
  float sc[2] = {};
  score_half(tid, Qs, 0, Bs, sc);
  __syncthreads();
  st64x(tid, ws + OFF_SET + b * 8192 + 4096, Bs);
  __syncthreads();
  score_half(tid, Qs, 64, Bs, sc);
  softmax_write(tid, sc, Wp, out + 2 * BNN + b * 4096 + rq * 1024);
  __syncthreads();
  // node = w @ av_act[b] (K=64)
  st128(tid, ws + OFF_AVACT + b * 8192, Bs, 64);
  __syncthreads();
  {
    float a[4] = {};
    g1(tid, Wp, 68, Bs, 64, a);
    epi<false, false>(tid, a, NB, 132, nullptr);
  }
  __syncthreads();
  // h_base = node @ Wf1^T (no activation; K=128, 2 chunks)
  st64x(tid, ws + OFF_WF1T, Bs);
  __syncthreads();
  float ah[2] = {};
  gH(tid, NB, 132, Bs, 64, ah);
  __syncthreads();
  st64x(tid, ws + OFF_WF1T + 4096, Bs);
  __syncthreads();
  gH(tid, NB + 64, 132, Bs, 64, ah);
  {
    const int c0 = (tid & 31) * 2, rg = tid >> 5;
    float2 v; v.x = ah[0]; v.y = ah[1];
    *reinterpret_cast<float2*>(&Hb[rg * 66 + c0]) = v;
  }
  __syncthreads();
  // head: value[i][j] = sum_f lrelu(Hb[i,f] + w[i,j]*Hd[j,f]) * Wf2[f]
  const int j = tid & 63, iw = tid >> 6;
  float wv[2], a2[2] = {0.f, 0.f};
#pragma unroll
  for (int r = 0; r < 2; ++r) wv[r] = Wp[(iw * 2 + r) * 68 + j];
  for (int f = 0; f < 64; ++f) {
    const float hdv = Hd[j * 69 + f];
    const float wf = Wf2s[f];
#pragma unroll
    for (int r = 0; r < 2; ++r) {
      float t = Hb[(iw * 2 + r) * 66 + f] + wv[r] * hdv;
      t = (t > 0.f) ? t : NSLOPE * t;
      a2[r] += t * wf;
    }
  }
#pragma unroll
  for (int r = 0; r < 2; ++r)
    out[(r0g + iw * 2 + r) * 64 + j] = a2[r];
}

extern "C" void kernel_launch(void* const* d_in, const int* in_sizes, int n_in,
                              void* d_out, int out_size, void* d_ws, size_t ws_size,
                              hipStream_t stream) {
  const float* states   = (const float*)d_in[0];
  const float* policies = (const float*)d_in[1];
  const float* actions  = (const float*)d_in[2];
  const float* W_se_pre = (const float*)d_in[3];
  const float* b_se_pre = (const float*)d_in[4];
  const float* W_key    = (const float*)d_in[5];
  const float* W_query  = (const float*)d_in[6];
  const float* W_se     = (const float*)d_in[7];
  const float* b_se     = (const float*)d_in[8];
  const float* W_sap    = (const float*)d_in[9];
  const float* b_sap    = (const float*)d_in[10];
  const float* W_av     = (const float*)d_in[11];
  const float* W_f1     = (const float*)d_in[12];
  const float* W_f2     = (const float*)d_in[13];
  float* out = (float*)d_out;
  float* ws  = (float*)d_ws;

  transpose_all<<<dim3(64, 6), dim3(256), 0, stream>>>(
      W_se_pre, W_query, W_se, W_sap, W_av, W_f1, ws);
  make_M<<<dim3(8), dim3(512), 0, stream>>>(W_key, ws);
  P1<<<dim3(256), dim3(512), 0, stream>>>(states, policies, actions, b_sap, b_se_pre, ws);
  P3<<<dim3(256), dim3(512), 0, stream>>>(b_se, ws, out);
  P4<<<dim3(256), dim3(512), 0, stream>>>(W_f2, ws, out);
}